// Round 11
// baseline (890.336 us; speedup 1.0000x reference)
//
#include <hip/hip_runtime.h>
#include <hip/hip_bf16.h>
#include <math.h>

#define MUL 8
#define NCOL 144   // 16*(1+3+5)
#define EREC 56    // per-slot record: t0[16] t1[16] t2[16] y1[3] y2[5]
#define SPAD 60    // LDS stage stride in floats

typedef __attribute__((ext_vector_type(8))) short short8;
typedef __attribute__((ext_vector_type(4))) float f32x4;

__device__ __forceinline__ float silu_f(float x) { return x / (1.0f + __expf(-x)); }

__device__ __forceinline__ unsigned short bf16_rn(float x) {
    unsigned u = __float_as_uint(x);
    unsigned r = u + 0x7FFF + ((u >> 16) & 1);
    return (unsigned short)(r >> 16);
}

// ---------------- node MLP -> Ai[N][8] ----------------
__global__ void node_mlp_kernel(const int* __restrict__ A,
                                const float* __restrict__ emb_table,
                                const float* __restrict__ w1,
                                const float* __restrict__ b1,
                                const float* __restrict__ w2,
                                const float* __restrict__ b2,
                                float* __restrict__ Ai, int N) {
    __shared__ float s_w1[16 * 64];
    __shared__ float s_w2[64 * MUL];
    __shared__ float s_b1[64];
    __shared__ float s_b2[MUL];
    __shared__ float s_emb[10 * 16];
    for (int i = threadIdx.x; i < 16 * 64; i += blockDim.x) s_w1[i] = w1[i];
    for (int i = threadIdx.x; i < 64 * MUL; i += blockDim.x) s_w2[i] = w2[i];
    for (int i = threadIdx.x; i < 64; i += blockDim.x) s_b1[i] = b1[i];
    for (int i = threadIdx.x; i < MUL; i += blockDim.x) s_b2[i] = b2[i];
    for (int i = threadIdx.x; i < 160; i += blockDim.x) s_emb[i] = emb_table[i];
    __syncthreads();

    int n = blockIdx.x * blockDim.x + threadIdx.x;
    if (n >= N) return;
    int a = A[n];

    float h[64];
    #pragma unroll
    for (int j = 0; j < 64; j++) h[j] = s_b1[j];
    #pragma unroll 1
    for (int k = 0; k < 16; k++) {
        float ek = s_emb[a * 16 + k];
        #pragma unroll
        for (int j = 0; j < 64; j++) h[j] += ek * s_w1[k * 64 + j];
    }
    #pragma unroll
    for (int j = 0; j < 64; j++) h[j] = silu_f(h[j]);

    #pragma unroll 1
    for (int u = 0; u < MUL; u++) {
        float acc = s_b2[u];
        #pragma unroll
        for (int k = 0; k < 64; k++) acc += h[k] * s_w2[k * MUL + u];
        Ai[n * MUL + u] = acc;
    }
}

// ---------------- CSR build ----------------
__global__ void count_kernel(const int* __restrict__ edst, int* __restrict__ count, int E) {
    int e = blockIdx.x * blockDim.x + threadIdx.x;
    if (e < E) atomicAdd(&count[edst[e]], 1);
}

__global__ void scan_kernel(const int* __restrict__ count, int* __restrict__ off, int N) {
    __shared__ int sums[1024];
    int L = N + 1;
    int chunk = (L + 1023) / 1024;
    int t = threadIdx.x;
    int lo = t * chunk;
    int hi = lo + chunk; if (hi > L) hi = L;
    int local = 0;
    for (int i = lo; i < hi; i++) local += (i < N) ? count[i] : 0;
    sums[t] = local;
    __syncthreads();
    for (int s = 1; s < 1024; s <<= 1) {
        int v = (t >= s) ? sums[t - s] : 0;
        __syncthreads();
        sums[t] += v;
        __syncthreads();
    }
    int run = (t == 0) ? 0 : sums[t - 1];
    for (int i = lo; i < hi; i++) {
        off[i] = run;
        run += (i < N) ? count[i] : 0;
    }
}

__global__ void fill_kernel(const int* __restrict__ edst, const int* __restrict__ off,
                            int* __restrict__ cursor, int* __restrict__ list, int E) {
    int e = blockIdx.x * blockDim.x + threadIdx.x;
    if (e >= E) return;
    int d = edst[e];
    int p = atomicAdd(&cursor[d], 1);
    list[off[d] + p] = e;   // slot -> edge id
}

// ---------------- phase A: per-CSR-slot compute -> contiguous 56-float record ----------------
// Bilinear t = p @ W done with MFMA (bf16 hi/lo split, 3-term).
__global__ void __launch_bounds__(256) edge_compute_kernel(
        const float* __restrict__ pos, const int* __restrict__ batch,
        const int* __restrict__ esrc, const int* __restrict__ edst,
        const float* __restrict__ shifts, const float* __restrict__ cell,
        const float* __restrict__ fw1, const float* __restrict__ fb1,
        const float* __restrict__ fw2, const float* __restrict__ fb2,
        const float* __restrict__ fw3, const float* __restrict__ fb3,
        const float* __restrict__ tpw,
        const float* __restrict__ Ai, const int* __restrict__ list,
        float* __restrict__ ebuf, int E) {
    __shared__ float s_w1[16 * 64];    // [k][j] j-consecutive
    __shared__ float s_w2t[64 * 64];   // transposed: [j][k] k-consecutive
    __shared__ float s_w3[64 * 3];
    __shared__ float s_b1[64];
    __shared__ float s_b2[64];
    __shared__ float s_b3[4];
    __shared__ float s_g[4 * 3 * 64];          // gates per wave/l/edge
    __shared__ unsigned int s_p[4 * 2048];     // per-wave packed p: [k'(32)][edge(64)]
    __shared__ float s_stage[64 * SPAD];

    const int tid  = threadIdx.x;
    const int wave = tid >> 6;
    const int lane = tid & 63;
    const int lw   = lane & 15;    // n / m index
    const int q    = lane >> 4;    // quad

    for (int i = tid; i < 1024; i += 256) s_w1[i] = fw1[i];
    for (int i = tid; i < 4096; i += 256) {
        int j = i >> 6, k = i & 63;
        s_w2t[i] = fw2[k * 64 + j];
    }
    for (int i = tid; i < 64; i += 256) { s_b1[i] = fb1[i]; s_b2[i] = fb2[i]; }
    for (int i = tid; i < 192; i += 256) {
        int j = i / 3, c = i - 3 * j;
        int cc = (c == 0) ? 0 : ((c == 1) ? 3 : 9);
        s_w3[i] = fw3[j * 15 + cc];
    }
    if (tid < 3) {
        int cc = (tid == 0) ? 0 : ((tid == 1) ? 3 : 9);
        s_b3[tid] = fb3[cc];
    }

    // ---- B-fragments for the bilinear GEMM: W[k=uv][n=w], hi/lo bf16 ----
    // lane holds B[k = 32h + q*8 + j][n = lw]
    short8 bh[2][3], bl[2][3];
    {
        const int pl[3] = {0, 3, 9};
        #pragma unroll
        for (int h = 0; h < 2; h++)
            #pragma unroll
            for (int li = 0; li < 3; li++)
                #pragma unroll
                for (int j = 0; j < 8; j++) {
                    int kg = 32 * h + q * 8 + j;
                    float w = tpw[pl[li] * 1024 + kg * 16 + lw];
                    unsigned short hi = bf16_rn(w);
                    float fh = __uint_as_float(((unsigned)hi) << 16);
                    unsigned short lo = bf16_rn(w - fh);
                    bh[h][li][j] = (short)hi;
                    bl[h][li][j] = (short)lo;
                }
    }
    __syncthreads();

    int slot = blockIdx.x * 256 + tid;
    bool active = (slot < E);

    float As[8], Ad[8];
    #pragma unroll
    for (int u = 0; u < 8; u++) { As[u] = 0.f; Ad[u] = 0.f; }
    float y10 = 0.f, y11 = 0.f, y12 = 0.f, y20 = 0.f, y21 = 0.f, y22 = 0.f, y23 = 0.f, y24 = 0.f;

    if (active) {
        int e = list[slot];
        int s = esrc[e], d = edst[e];
        int g = batch[s];
        float sh0 = shifts[e * 3 + 0], sh1 = shifts[e * 3 + 1], sh2 = shifts[e * 3 + 2];
        const float* cg = cell + g * 9;
        float sv0 = sh0 * cg[0] + sh1 * cg[3] + sh2 * cg[6];
        float sv1 = sh0 * cg[1] + sh1 * cg[4] + sh2 * cg[7];
        float sv2 = sh0 * cg[2] + sh1 * cg[5] + sh2 * cg[8];
        float vx = pos[d * 3 + 0] - pos[s * 3 + 0] + sv0;
        float vy = pos[d * 3 + 1] - pos[s * 3 + 1] + sv1;
        float vz = pos[d * 3 + 2] - pos[s * 3 + 2] + sv2;
        float len = sqrtf(vx * vx + vy * vy + vz * vz);
        float inv = 1.0f / fmaxf(len, 1e-8f);
        float nx = vx * inv, ny = vy * inv, nz = vz * inv;

        // ---- radial MLP (VALU, LDS weights) ----
        float r = len * (17.0f / 5.0f);
        float4 h4[16];
        const float4* b1_4 = (const float4*)s_b1;
        #pragma unroll
        for (int j4 = 0; j4 < 16; j4++) h4[j4] = b1_4[j4];
        #pragma unroll 1
        for (int k = 0; k < 16; k++) {
            float dk = r - (float)(k + 1);
            float ek = __expf(-dk * dk) * (4.0f / 1.12f);
            const float4* w1r = (const float4*)(s_w1 + (k << 6));
            #pragma unroll
            for (int j4 = 0; j4 < 16; j4++) {
                float4 w = w1r[j4];
                h4[j4].x += ek * w.x; h4[j4].y += ek * w.y;
                h4[j4].z += ek * w.z; h4[j4].w += ek * w.w;
            }
        }
        #pragma unroll
        for (int j4 = 0; j4 < 16; j4++) {
            h4[j4].x = silu_f(h4[j4].x); h4[j4].y = silu_f(h4[j4].y);
            h4[j4].z = silu_f(h4[j4].z); h4[j4].w = silu_f(h4[j4].w);
        }

        float g0 = s_b3[0], g1 = s_b3[1], g2 = s_b3[2];
        #pragma unroll 2
        for (int j = 0; j < 64; j++) {
            const float4* w2r = (const float4*)(s_w2t + (j << 6));
            float a = s_b2[j];
            #pragma unroll
            for (int k4 = 0; k4 < 16; k4++) {
                float4 w = w2r[k4];
                a += h4[k4].x * w.x + h4[k4].y * w.y + h4[k4].z * w.z + h4[k4].w * w.w;
            }
            a = silu_f(a);
            g0 += a * s_w3[j * 3 + 0];
            g1 += a * s_w3[j * 3 + 1];
            g2 += a * s_w3[j * 3 + 2];
        }
        g0 *= 0.125f; g1 *= 0.125f; g2 *= 0.125f;   // PATH_NORM

        s_g[wave * 192 + 0 * 64 + lane] = g0;
        s_g[wave * 192 + 1 * 64 + lane] = g1;
        s_g[wave * 192 + 2 * 64 + lane] = g2;

        const float4* Ad4p = (const float4*)(Ai + d * MUL);
        float4 a0 = Ad4p[0], a1 = Ad4p[1];
        Ad[0] = a0.x; Ad[1] = a0.y; Ad[2] = a0.z; Ad[3] = a0.w;
        Ad[4] = a1.x; Ad[5] = a1.y; Ad[6] = a1.z; Ad[7] = a1.w;
        const float4* As4p = (const float4*)(Ai + s * MUL);
        float4 b0 = As4p[0], b1v = As4p[1];
        As[0] = b0.x; As[1] = b0.y; As[2] = b0.z; As[3] = b0.w;
        As[4] = b1v.x; As[5] = b1v.y; As[6] = b1v.z; As[7] = b1v.w;

        const float s3 = 1.7320508075688772f;
        const float s15 = 3.872983346207417f;
        const float s5h = 1.118033988749895f;
        y10 = s3 * nx; y11 = s3 * ny; y12 = s3 * nz;
        y20 = s15 * nx * ny; y21 = s15 * ny * nz; y22 = s5h * (3.f * nz * nz - 1.f);
        y23 = s15 * nx * nz; y24 = 0.5f * s15 * (nx * nx - ny * ny);
    }

    // ---- bilinear via MFMA: two K-halves ----
    f32x4 acc[3][4];
    #pragma unroll
    for (int li = 0; li < 3; li++)
        #pragma unroll
        for (int tt = 0; tt < 4; tt++) acc[li][tt] = (f32x4){0.f, 0.f, 0.f, 0.f};

    unsigned int* pbase = s_p + wave * 2048;

    #pragma unroll 1
    for (int h = 0; h < 2; h++) {
        __syncthreads();
        // write packed p for k' = 0..31 (k_global = 32h + k')
        #pragma unroll
        for (int c = 0; c < 32; c++) {
            int u = 4 * h + (c >> 3), v = c & 7;
            float pv = As[u] * Ad[v];
            unsigned short hi = bf16_rn(pv);
            float fh = __uint_as_float(((unsigned)hi) << 16);
            unsigned short lo = bf16_rn(pv - fh);
            pbase[c * 64 + lane] = (((unsigned)hi) << 16) | (unsigned)lo;
        }
        __syncthreads();
        // MFMA over the wave's 4 edge-tiles
        #pragma unroll
        for (int tt = 0; tt < 4; tt++) {
            unsigned int aw[8];
            #pragma unroll
            for (int j = 0; j < 8; j++) aw[j] = pbase[(q * 8 + j) * 64 + tt * 16 + lw];
            short8 ahi, alo;
            #pragma unroll
            for (int j = 0; j < 8; j++) {
                ahi[j] = (short)(aw[j] >> 16);
                alo[j] = (short)(aw[j] & 0xFFFF);
            }
            #pragma unroll
            for (int li = 0; li < 3; li++) {
                acc[li][tt] = __builtin_amdgcn_mfma_f32_16x16x32_bf16(ahi, bh[h][li], acc[li][tt], 0, 0, 0);
                acc[li][tt] = __builtin_amdgcn_mfma_f32_16x16x32_bf16(alo, bh[h][li], acc[li][tt], 0, 0, 0);
                acc[li][tt] = __builtin_amdgcn_mfma_f32_16x16x32_bf16(ahi, bl[h][li], acc[li][tt], 0, 0, 0);
            }
        }
    }

    // ---- staged coalesced write ----
    float4* st4 = (float4*)s_stage;
    float4* eb4 = (float4*)ebuf;
    #pragma unroll 1
    for (int rnd = 0; rnd < 4; rnd++) {
        __syncthreads();
        if (wave == rnd) {
            if (active) {
                float4* dst = (float4*)(s_stage + lane * SPAD);
                dst[12] = make_float4(y10, y11, y12, y20);
                dst[13] = make_float4(y21, y22, y23, y24);
            }
            // t-part from MFMA C-layout: col=lw (w), row=q*4+reg (edge in tile)
            #pragma unroll
            for (int li = 0; li < 3; li++)
                #pragma unroll
                for (int tt = 0; tt < 4; tt++)
                    #pragma unroll
                    for (int reg = 0; reg < 4; reg++) {
                        int eL = tt * 16 + q * 4 + reg;
                        float gv = s_g[wave * 192 + li * 64 + eL];
                        s_stage[eL * SPAD + li * 16 + lw] = acc[li][tt][reg] * gv;
                    }
        }
        __syncthreads();
        long long base_s = (long long)blockIdx.x * 256 + rnd * 64;
        #pragma unroll
        for (int k = 0; k < 4; k++) {
            int idx = tid + k * 256;
            if (idx < 64 * 14) {
                int le = idx / 14, comp = idx - le * 14;
                long long gs = base_s + le;
                if (gs < E) eb4[gs * 14 + comp] = st4[le * (SPAD / 4) + comp];
            }
        }
    }
}

// ---------------- phase B: streaming gather, 1 node / 192 threads, 4-way unroll ----------------
__global__ void __launch_bounds__(192) gather_kernel(
        const float* __restrict__ ebuf, const int* __restrict__ off,
        float* __restrict__ out, int N) {
    int n = blockIdx.x;
    int c = threadIdx.x;
    if (c >= NCOL) return;
    int b = off[n], eN = off[n + 1];
    float val = 0.f;
    if (c < 16) {
        int j = b;
        for (; j + 4 <= eN; j += 4) {
            float a0 = ebuf[(size_t)(j + 0) * EREC + c];
            float a1 = ebuf[(size_t)(j + 1) * EREC + c];
            float a2 = ebuf[(size_t)(j + 2) * EREC + c];
            float a3 = ebuf[(size_t)(j + 3) * EREC + c];
            val += (a0 + a1) + (a2 + a3);
        }
        for (; j < eN; j++) val += ebuf[(size_t)j * EREC + c];
    } else if (c < 64) {
        int rr = c - 16, w = rr / 3, i = rr - 3 * w;
        int o1 = 16 + w, o2 = 48 + i;
        int j = b;
        for (; j + 4 <= eN; j += 4) {
            const float* r0 = ebuf + (size_t)(j + 0) * EREC;
            const float* r1 = ebuf + (size_t)(j + 1) * EREC;
            const float* r2 = ebuf + (size_t)(j + 2) * EREC;
            const float* r3 = ebuf + (size_t)(j + 3) * EREC;
            float a0 = r0[o1] * r0[o2];
            float a1 = r1[o1] * r1[o2];
            float a2 = r2[o1] * r2[o2];
            float a3 = r3[o1] * r3[o2];
            val += (a0 + a1) + (a2 + a3);
        }
        for (; j < eN; j++) {
            const float* rec = ebuf + (size_t)j * EREC;
            val += rec[o1] * rec[o2];
        }
    } else {
        int rr = c - 64, w = rr / 5, i = rr - 5 * w;
        int o1 = 32 + w, o2 = 51 + i;
        int j = b;
        for (; j + 4 <= eN; j += 4) {
            const float* r0 = ebuf + (size_t)(j + 0) * EREC;
            const float* r1 = ebuf + (size_t)(j + 1) * EREC;
            const float* r2 = ebuf + (size_t)(j + 2) * EREC;
            const float* r3 = ebuf + (size_t)(j + 3) * EREC;
            float a0 = r0[o1] * r0[o2];
            float a1 = r1[o1] * r1[o2];
            float a2 = r2[o1] * r2[o2];
            float a3 = r3[o1] * r3[o2];
            val += (a0 + a1) + (a2 + a3);
        }
        for (; j < eN; j++) {
            const float* rec = ebuf + (size_t)j * EREC;
            val += rec[o1] * rec[o2];
        }
    }
    float dg = (float)(eN - b);
    out[(size_t)n * NCOL + c] = val / fmaxf(dg, 1.0f);
}

// ================= fallback (small ws): atomic path =================
__global__ void __launch_bounds__(256) edge_atomic_kernel(
        const float* __restrict__ pos, const int* __restrict__ batch,
        const int* __restrict__ esrc, const int* __restrict__ edst,
        const float* __restrict__ shifts, const float* __restrict__ cell,
        const float* __restrict__ fw1, const float* __restrict__ fb1,
        const float* __restrict__ fw2, const float* __restrict__ fb2,
        const float* __restrict__ fw3, const float* __restrict__ fb3,
        const float* __restrict__ tpw,
        const float* __restrict__ Ai,
        float* __restrict__ out, float* __restrict__ deg, int E) {
    __shared__ float s_w1[16 * 64];
    __shared__ float s_w2[64 * 64];
    __shared__ float s_w3[64 * 3];
    __shared__ float s_b1[64];
    __shared__ float s_b2[64];
    __shared__ float s_b3[3];
    __shared__ float s_tpw[3 * 1024];
    for (int i = threadIdx.x; i < 1024; i += blockDim.x) s_w1[i] = fw1[i];
    for (int i = threadIdx.x; i < 4096; i += blockDim.x) s_w2[i] = fw2[i];
    for (int i = threadIdx.x; i < 64; i += blockDim.x) { s_b1[i] = fb1[i]; s_b2[i] = fb2[i]; }
    for (int i = threadIdx.x; i < 192; i += blockDim.x) {
        int j = i / 3, c = i - 3 * j;
        int cc = (c == 0) ? 0 : ((c == 1) ? 3 : 9);
        s_w3[i] = fw3[j * 15 + cc];
    }
    if (threadIdx.x < 3) {
        int cc = (threadIdx.x == 0) ? 0 : ((threadIdx.x == 1) ? 3 : 9);
        s_b3[threadIdx.x] = fb3[cc];
    }
    for (int i = threadIdx.x; i < 3 * 1024; i += blockDim.x) {
        int l = i >> 10, r = i & 1023;
        int p = (l == 0) ? 0 : ((l == 1) ? 3 : 9);
        s_tpw[i] = tpw[p * 1024 + r];
    }
    __syncthreads();
    int e = blockIdx.x * blockDim.x + threadIdx.x;
    if (e >= E) return;
    int s = esrc[e], d = edst[e];
    int g = batch[s];
    float sh0 = shifts[e * 3 + 0], sh1 = shifts[e * 3 + 1], sh2 = shifts[e * 3 + 2];
    const float* cg = cell + g * 9;
    float sv0 = sh0 * cg[0] + sh1 * cg[3] + sh2 * cg[6];
    float sv1 = sh0 * cg[1] + sh1 * cg[4] + sh2 * cg[7];
    float sv2 = sh0 * cg[2] + sh1 * cg[5] + sh2 * cg[8];
    float vx = pos[d * 3 + 0] - pos[s * 3 + 0] + sv0;
    float vy = pos[d * 3 + 1] - pos[s * 3 + 1] + sv1;
    float vz = pos[d * 3 + 2] - pos[s * 3 + 2] + sv2;
    float len = sqrtf(vx * vx + vy * vy + vz * vz);
    float inv = 1.0f / fmaxf(len, 1e-8f);
    float nx = vx * inv, ny = vy * inv, nz = vz * inv;
    float r = len * (17.0f / 5.0f);
    float h[64];
    #pragma unroll
    for (int j = 0; j < 64; j++) h[j] = s_b1[j];
    #pragma unroll 1
    for (int k = 0; k < 16; k++) {
        float dk = r - (float)(k + 1);
        float ek = __expf(-dk * dk) * (4.0f / 1.12f);
        #pragma unroll
        for (int j = 0; j < 64; j++) h[j] += ek * s_w1[k * 64 + j];
    }
    #pragma unroll
    for (int j = 0; j < 64; j++) h[j] = silu_f(h[j]);
    float g0 = s_b3[0], g1 = s_b3[1], g2 = s_b3[2];
    #pragma unroll 2
    for (int j = 0; j < 64; j++) {
        float a = s_b2[j];
        #pragma unroll
        for (int k = 0; k < 64; k++) a += h[k] * s_w2[k * 64 + j];
        a = silu_f(a);
        g0 += a * s_w3[j * 3 + 0];
        g1 += a * s_w3[j * 3 + 1];
        g2 += a * s_w3[j * 3 + 2];
    }
    g0 *= 0.125f; g1 *= 0.125f; g2 *= 0.125f;
    float t0[16], t1[16], t2[16];
    #pragma unroll
    for (int w = 0; w < 16; w++) { t0[w] = 0.f; t1[w] = 0.f; t2[w] = 0.f; }
    int s8 = s * MUL, d8 = d * MUL;
    float Ad[8];
    #pragma unroll
    for (int v = 0; v < 8; v++) Ad[v] = Ai[d8 + v];
    #pragma unroll 1
    for (int u = 0; u < 8; u++) {
        float asu = Ai[s8 + u];
        int offp = u * 128;
        #pragma unroll
        for (int v = 0; v < 8; v++) {
            float p = asu * Ad[v];
            int o2 = offp + v * 16;
            #pragma unroll
            for (int w = 0; w < 16; w++) {
                t0[w] += p * s_tpw[o2 + w];
                t1[w] += p * s_tpw[1024 + o2 + w];
                t2[w] += p * s_tpw[2048 + o2 + w];
            }
        }
    }
    #pragma unroll
    for (int w = 0; w < 16; w++) { t0[w] *= g0; t1[w] *= g1; t2[w] *= g2; }
    const float s3 = 1.7320508075688772f;
    const float s15 = 3.872983346207417f;
    const float s5h = 1.118033988749895f;
    float y1_[3] = { s3 * nx, s3 * ny, s3 * nz };
    float y2_[5] = { s15 * nx * ny, s15 * ny * nz, s5h * (3.f * nz * nz - 1.f),
                     s15 * nx * nz, 0.5f * s15 * (nx * nx - ny * ny) };
    float* o = out + (size_t)d * NCOL;
    #pragma unroll
    for (int w = 0; w < 16; w++) atomicAdd(o + w, t0[w]);
    #pragma unroll
    for (int w = 0; w < 16; w++)
        #pragma unroll
        for (int i = 0; i < 3; i++) atomicAdd(o + 16 + w * 3 + i, t1[w] * y1_[i]);
    #pragma unroll
    for (int w = 0; w < 16; w++)
        #pragma unroll
        for (int i = 0; i < 5; i++) atomicAdd(o + 64 + w * 5 + i, t2[w] * y2_[i]);
    atomicAdd(deg + d, 1.0f);
}

__global__ void finalize_kernel(float* __restrict__ out, const float* __restrict__ deg, int total) {
    int idx = blockIdx.x * blockDim.x + threadIdx.x;
    if (idx >= total) return;
    int n = idx / NCOL;
    out[idx] = out[idx] / fmaxf(deg[n], 1.0f);
}

extern "C" void kernel_launch(void* const* d_in, const int* in_sizes, int n_in,
                              void* d_out, int out_size, void* d_ws, size_t ws_size,
                              hipStream_t stream) {
    const float* pos    = (const float*)d_in[0];
    const int*   A      = (const int*)d_in[1];
    const int*   batch  = (const int*)d_in[2];
    const int*   esrc   = (const int*)d_in[3];
    const int*   edst   = (const int*)d_in[4];
    const float* shifts = (const float*)d_in[5];
    const float* cellp  = (const float*)d_in[6];
    const float* embt   = (const float*)d_in[7];
    const float* aw1    = (const float*)d_in[8];
    const float* ab1    = (const float*)d_in[9];
    const float* aw2    = (const float*)d_in[10];
    const float* ab2    = (const float*)d_in[11];
    const float* fw1    = (const float*)d_in[12];
    const float* fb1    = (const float*)d_in[13];
    const float* fw2    = (const float*)d_in[14];
    const float* fb2    = (const float*)d_in[15];
    const float* fw3    = (const float*)d_in[16];
    const float* fb3    = (const float*)d_in[17];
    const float* tpw    = (const float*)d_in[18];

    int N = in_sizes[1];
    int E = in_sizes[3];
    float* out = (float*)d_out;

    size_t need = (size_t)N * 32 + (size_t)N * 4 * 2 + (size_t)(N + 1) * 4
                + (size_t)E * 4 + (size_t)E * EREC * 4 + 512;

    if (ws_size >= need) {
        float* Ai    = (float*)d_ws;
        int*   count = (int*)(Ai + (size_t)N * MUL);
        int*   cursor= count + N;
        int*   off   = cursor + N;
        int*   list  = off + (N + 1);
        float* ebuf  = (float*)(((uintptr_t)(list + E) + 255) & ~(uintptr_t)255);

        hipMemsetAsync(count, 0, (size_t)N * 2 * sizeof(int), stream);  // count + cursor

        node_mlp_kernel<<<(N + 255) / 256, 256, 0, stream>>>(A, embt, aw1, ab1, aw2, ab2, Ai, N);
        count_kernel<<<(E + 255) / 256, 256, 0, stream>>>(edst, count, E);
        scan_kernel<<<1, 1024, 0, stream>>>(count, off, N);
        fill_kernel<<<(E + 255) / 256, 256, 0, stream>>>(edst, off, cursor, list, E);

        edge_compute_kernel<<<(E + 255) / 256, 256, 0, stream>>>(
            pos, batch, esrc, edst, shifts, cellp,
            fw1, fb1, fw2, fb2, fw3, fb3, tpw, Ai, list, ebuf, E);

        gather_kernel<<<N, 192, 0, stream>>>(ebuf, off, out, N);
    } else {
        float* Ai  = (float*)d_ws;
        float* deg = Ai + (size_t)N * MUL;
        hipMemsetAsync(out, 0, (size_t)out_size * sizeof(float), stream);
        hipMemsetAsync(deg, 0, (size_t)N * sizeof(float), stream);
        node_mlp_kernel<<<(N + 255) / 256, 256, 0, stream>>>(A, embt, aw1, ab1, aw2, ab2, Ai, N);
        edge_atomic_kernel<<<(E + 255) / 256, 256, 0, stream>>>(
            pos, batch, esrc, edst, shifts, cellp,
            fw1, fb1, fw2, fb2, fw3, fb3, tpw, Ai, out, deg, E);
        int total = N * NCOL;
        finalize_kernel<<<(total + 255) / 256, 256, 0, stream>>>(out, deg, total);
    }
}

// Round 12
// 451.161 us; speedup vs baseline: 1.9734x; 1.9734x over previous
//
#include <hip/hip_runtime.h>
#include <hip/hip_bf16.h>
#include <math.h>

#define MUL 8
#define NCOL 144   // 16*(1+3+5)
#define TSIZE 8192
#define TMAXLEN 8.0f

__device__ __forceinline__ float silu_f(float x) { return x / (1.0f + __expf(-x)); }

// ---------------- node MLP -> Ai[N][8] ----------------
__global__ void node_mlp_kernel(const int* __restrict__ A,
                                const float* __restrict__ emb_table,
                                const float* __restrict__ w1,
                                const float* __restrict__ b1,
                                const float* __restrict__ w2,
                                const float* __restrict__ b2,
                                float* __restrict__ Ai, int N) {
    __shared__ float s_w1[16 * 64];
    __shared__ float s_w2[64 * MUL];
    __shared__ float s_b1[64];
    __shared__ float s_b2[MUL];
    __shared__ float s_emb[10 * 16];
    for (int i = threadIdx.x; i < 16 * 64; i += blockDim.x) s_w1[i] = w1[i];
    for (int i = threadIdx.x; i < 64 * MUL; i += blockDim.x) s_w2[i] = w2[i];
    for (int i = threadIdx.x; i < 64; i += blockDim.x) s_b1[i] = b1[i];
    for (int i = threadIdx.x; i < MUL; i += blockDim.x) s_b2[i] = b2[i];
    for (int i = threadIdx.x; i < 160; i += blockDim.x) s_emb[i] = emb_table[i];
    __syncthreads();

    int n = blockIdx.x * blockDim.x + threadIdx.x;
    if (n >= N) return;
    int a = A[n];

    float h[64];
    #pragma unroll
    for (int j = 0; j < 64; j++) h[j] = s_b1[j];
    #pragma unroll 1
    for (int k = 0; k < 16; k++) {
        float ek = s_emb[a * 16 + k];
        #pragma unroll
        for (int j = 0; j < 64; j++) h[j] += ek * s_w1[k * 64 + j];
    }
    #pragma unroll
    for (int j = 0; j < 64; j++) h[j] = silu_f(h[j]);

    #pragma unroll 1
    for (int u = 0; u < MUL; u++) {
        float acc = s_b2[u];
        #pragma unroll
        for (int k = 0; k < 64; k++) acc += h[k] * s_w2[k * MUL + u];
        Ai[n * MUL + u] = acc;
    }
}

// ---------------- gate table: g(len) for len in [0,8), pre-scaled by PATH_NORM ----------------
__global__ void gate_table_kernel(const float* __restrict__ fw1, const float* __restrict__ fb1,
                                  const float* __restrict__ fw2, const float* __restrict__ fb2,
                                  const float* __restrict__ fw3, const float* __restrict__ fb3,
                                  float4* __restrict__ tab) {
    int i = blockIdx.x * blockDim.x + threadIdx.x;
    if (i >= TSIZE) return;
    float len = (float)i * (TMAXLEN / TSIZE);
    float r = len * (17.0f / 5.0f);
    float h[64];
    #pragma unroll
    for (int j = 0; j < 64; j++) h[j] = fb1[j];
    #pragma unroll 1
    for (int k = 0; k < 16; k++) {
        float dk = r - (float)(k + 1);
        float ek = __expf(-dk * dk) * (4.0f / 1.12f);
        #pragma unroll
        for (int j = 0; j < 64; j++) h[j] += ek * fw1[k * 64 + j];
    }
    #pragma unroll
    for (int j = 0; j < 64; j++) h[j] = silu_f(h[j]);
    float g0 = fb3[0], g1 = fb3[3], g2 = fb3[9];
    #pragma unroll 1
    for (int j = 0; j < 64; j++) {
        float a = fb2[j];
        #pragma unroll
        for (int k = 0; k < 64; k++) a += h[k] * fw2[k * 64 + j];
        a = silu_f(a);
        g0 += a * fw3[j * 15 + 0];
        g1 += a * fw3[j * 15 + 3];
        g2 += a * fw3[j * 15 + 9];
    }
    tab[i] = make_float4(g0 * 0.125f, g1 * 0.125f, g2 * 0.125f, 0.f);
}

// ---------------- CSR build ----------------
__global__ void count_kernel(const int* __restrict__ edst, int* __restrict__ count, int E) {
    int e = blockIdx.x * blockDim.x + threadIdx.x;
    if (e < E) atomicAdd(&count[edst[e]], 1);
}

__global__ void scan_kernel(const int* __restrict__ count, int* __restrict__ off, int N) {
    __shared__ int sums[1024];
    int L = N + 1;
    int chunk = (L + 1023) / 1024;
    int t = threadIdx.x;
    int lo = t * chunk;
    int hi = lo + chunk; if (hi > L) hi = L;
    int local = 0;
    for (int i = lo; i < hi; i++) local += (i < N) ? count[i] : 0;
    sums[t] = local;
    __syncthreads();
    for (int s = 1; s < 1024; s <<= 1) {
        int v = (t >= s) ? sums[t - s] : 0;
        __syncthreads();
        sums[t] += v;
        __syncthreads();
    }
    int run = (t == 0) ? 0 : sums[t - 1];
    for (int i = lo; i < hi; i++) {
        off[i] = run;
        run += (i < N) ? count[i] : 0;
    }
}

__global__ void fill_kernel(const int* __restrict__ edst, const int* __restrict__ off,
                            int* __restrict__ cursor, int* __restrict__ list, int E) {
    int e = blockIdx.x * blockDim.x + threadIdx.x;
    if (e >= E) return;
    int d = edst[e];
    int p = atomicAdd(&cursor[d], 1);
    list[off[d] + p] = e;
}

// ---------------- fused conv: one wave per destination node ----------------
// out_l[w,i] = (1/cnt) * sum_u M_l[u,w] * Z_l[u,i]
//   M_l[u,w] = sum_v Ad[v] * W_l[u,v,w]        (per node, W in LDS transposed)
//   Z_l[u,i] = sum_e As_e[u] * g_l(e) * Y_l(e)[i]   (per edge; gates from table, PN folded)
__global__ void __launch_bounds__(256) conv_node_kernel(
        const float* __restrict__ pos, const int* __restrict__ batch,
        const int* __restrict__ esrc,
        const float* __restrict__ shifts, const float* __restrict__ cell,
        const float* __restrict__ tpw, const float4* __restrict__ gtab,
        const float* __restrict__ Ai, const int* __restrict__ off,
        const int* __restrict__ list,
        float* __restrict__ out, int N) {
    __shared__ float s_tpwT[3 * 1024];     // [l][u][w][v] v-consecutive
    __shared__ float s_stage[4][17 * 64];  // per-wave: rows q=0..16 (As[0..7], gy[0..8]) x 64 edges
    __shared__ float s_Z[4][80];
    __shared__ float s_M[4][388];          // [l*128 + w*8 + u]

    const int tid = threadIdx.x, wv = tid >> 6, lane = tid & 63;

    {
        const int pl[3] = {0, 3, 9};
        for (int i = tid; i < 3072; i += 256) {
            int l = i >> 10, r = i & 1023;
            int u = r >> 7, v = (r >> 4) & 7, w = r & 15;
            s_tpwT[(l << 10) + (u << 7) + (w << 3) + v] = tpw[pl[l] * 1024 + r];
        }
    }
    __syncthreads();

    int n = blockIdx.x * 4 + wv;
    bool nv = (n < N);
    int b0 = nv ? off[n] : 0;
    int b1 = nv ? off[n + 1] : 0;
    int deg = b1 - b0;

    float z0 = 0.f, z1 = 0.f;
    int u0 = lane / 9, i0 = lane - 9 * u0;
    int e1i = 64 + lane;
    int u1 = e1i / 9, i1 = e1i - 9 * u1;   // used when lane < 8
    float* st = s_stage[wv];

    float px = 0.f, py = 0.f, pz = 0.f;
    if (nv && deg > 0) { px = pos[n * 3 + 0]; py = pos[n * 3 + 1]; pz = pos[n * 3 + 2]; }

    int nrnd = (deg + 63) >> 6;
    #pragma unroll 1
    for (int rnd = 0; rnd < nrnd; rnd++) {
        int base = rnd << 6;
        int slot = b0 + base + lane;
        float As[8], gy[9];
        #pragma unroll
        for (int u = 0; u < 8; u++) As[u] = 0.f;
        #pragma unroll
        for (int i = 0; i < 9; i++) gy[i] = 0.f;
        if (slot < b1) {
            int e = list[slot];
            int s = esrc[e];
            int g = batch[s];
            float sh0 = shifts[e * 3 + 0], sh1 = shifts[e * 3 + 1], sh2 = shifts[e * 3 + 2];
            const float* cg = cell + g * 9;
            float sv0 = sh0 * cg[0] + sh1 * cg[3] + sh2 * cg[6];
            float sv1 = sh0 * cg[1] + sh1 * cg[4] + sh2 * cg[7];
            float sv2 = sh0 * cg[2] + sh1 * cg[5] + sh2 * cg[8];
            float vx = px - pos[s * 3 + 0] + sv0;   // dst = n
            float vy = py - pos[s * 3 + 1] + sv1;
            float vz = pz - pos[s * 3 + 2] + sv2;
            float len = sqrtf(vx * vx + vy * vy + vz * vz);
            float inv = 1.0f / fmaxf(len, 1e-8f);
            float nx = vx * inv, ny = vy * inv, nz = vz * inv;

            float tp = fminf(len * ((float)TSIZE / TMAXLEN), (float)(TSIZE - 1));
            int ti = (int)tp; if (ti > TSIZE - 2) ti = TSIZE - 2;
            float fr = tp - (float)ti;
            float4 ga = gtab[ti], gb = gtab[ti + 1];
            float g0 = ga.x + fr * (gb.x - ga.x);
            float g1 = ga.y + fr * (gb.y - ga.y);
            float g2 = ga.z + fr * (gb.z - ga.z);

            const float s3c = 1.7320508075688772f;
            const float s15 = 3.872983346207417f;
            const float s5h = 1.118033988749895f;
            gy[0] = g0;
            gy[1] = g1 * (s3c * nx); gy[2] = g1 * (s3c * ny); gy[3] = g1 * (s3c * nz);
            gy[4] = g2 * (s15 * nx * ny); gy[5] = g2 * (s15 * ny * nz);
            gy[6] = g2 * (s5h * (3.f * nz * nz - 1.f));
            gy[7] = g2 * (s15 * nx * nz); gy[8] = g2 * (0.5f * s15 * (nx * nx - ny * ny));

            const float4* Ap = (const float4*)(Ai + s * MUL);
            float4 A0 = Ap[0], A1 = Ap[1];
            As[0] = A0.x; As[1] = A0.y; As[2] = A0.z; As[3] = A0.w;
            As[4] = A1.x; As[5] = A1.y; As[6] = A1.z; As[7] = A1.w;
        }
        // stage transposed: row q, column = lane (conflict-free writes)
        #pragma unroll
        for (int u = 0; u < 8; u++) st[u * 64 + lane] = As[u];
        #pragma unroll
        for (int i = 0; i < 9; i++) st[(8 + i) * 64 + lane] = gy[i];
        __builtin_amdgcn_wave_barrier();
        int jmax = deg - base; if (jmax > 64) jmax = 64;
        int j4 = (jmax + 3) >> 2;
        {
            const float4* ru  = (const float4*)(st + u0 * 64);
            const float4* ri  = (const float4*)(st + (8 + i0) * 64);
            const float4* ru1 = (const float4*)(st + u1 * 64);
            const float4* ri1 = (const float4*)(st + (8 + i1) * 64);
            #pragma unroll 1
            for (int j = 0; j < j4; j++) {
                float4 a = ru[j], b = ri[j];
                z0 += a.x * b.x + a.y * b.y + a.z * b.z + a.w * b.w;
                if (lane < 8) {
                    float4 c = ru1[j], d = ri1[j];
                    z1 += c.x * d.x + c.y * d.y + c.z * d.z + c.w * d.w;
                }
            }
        }
        __builtin_amdgcn_wave_barrier();
    }

    // publish Z (72 elements, elem = u*9 + i)
    s_Z[wv][lane] = z0;
    if (lane < 8) s_Z[wv][64 + lane] = z1;

    float Ad[8];
    #pragma unroll
    for (int v = 0; v < 8; v++) Ad[v] = nv ? Ai[n * MUL + v] : 0.f;
    __builtin_amdgcn_wave_barrier();

    // M: 384 elements, 6 per lane; store [l*128 + w*8 + u]
    float* M = s_M[wv];
    #pragma unroll
    for (int t = 0; t < 6; t++) {
        int m = lane + (t << 6);
        int l = m >> 7, r = m & 127, u = r >> 4, w = r & 15;
        const float4* tw = (const float4*)(s_tpwT + (l << 10) + (u << 7) + (w << 3));
        float4 wa = tw[0], wb = tw[1];
        float acc = Ad[0] * wa.x + Ad[1] * wa.y + Ad[2] * wa.z + Ad[3] * wa.w
                  + Ad[4] * wb.x + Ad[5] * wb.y + Ad[6] * wb.z + Ad[7] * wb.w;
        M[(l << 7) + (w << 3) + u] = acc;
    }
    __builtin_amdgcn_wave_barrier();

    float dinv = 1.0f / fmaxf((float)deg, 1.0f);
    float* Z = s_Z[wv];
    if (nv) {
        #pragma unroll
        for (int t = 0; t < 3; t++) {
            int c = lane + (t << 6);
            if (c < NCOL) {
                int l, w, ii;
                if (c < 16)      { l = 0; w = c;            ii = 0; }
                else if (c < 64) { l = 1; w = (c - 16) / 3; ii = 1 + (c - 16) % 3; }
                else             { l = 2; w = (c - 64) / 5; ii = 4 + (c - 64) % 5; }
                const float4* mm = (const float4*)(M + (l << 7) + (w << 3));
                float4 m0 = mm[0], m1 = mm[1];
                float val = m0.x * Z[0 * 9 + ii] + m0.y * Z[1 * 9 + ii]
                          + m0.z * Z[2 * 9 + ii] + m0.w * Z[3 * 9 + ii]
                          + m1.x * Z[4 * 9 + ii] + m1.y * Z[5 * 9 + ii]
                          + m1.z * Z[6 * 9 + ii] + m1.w * Z[7 * 9 + ii];
                out[(size_t)n * NCOL + c] = val * dinv;
            }
        }
    }
}

// ================= fallback (small ws): atomic path (R10, proven) =================
__global__ void __launch_bounds__(256) edge_atomic_kernel(
        const float* __restrict__ pos, const int* __restrict__ batch,
        const int* __restrict__ esrc, const int* __restrict__ edst,
        const float* __restrict__ shifts, const float* __restrict__ cell,
        const float* __restrict__ fw1, const float* __restrict__ fb1,
        const float* __restrict__ fw2, const float* __restrict__ fb2,
        const float* __restrict__ fw3, const float* __restrict__ fb3,
        const float* __restrict__ tpw,
        const float* __restrict__ Ai,
        float* __restrict__ out, float* __restrict__ deg, int E) {
    __shared__ float s_w1[16 * 64];
    __shared__ float s_w2[64 * 64];
    __shared__ float s_w3[64 * 3];
    __shared__ float s_b1[64];
    __shared__ float s_b2[64];
    __shared__ float s_b3[3];
    __shared__ float s_tpw[3 * 1024];
    for (int i = threadIdx.x; i < 1024; i += blockDim.x) s_w1[i] = fw1[i];
    for (int i = threadIdx.x; i < 4096; i += blockDim.x) s_w2[i] = fw2[i];
    for (int i = threadIdx.x; i < 64; i += blockDim.x) { s_b1[i] = fb1[i]; s_b2[i] = fb2[i]; }
    for (int i = threadIdx.x; i < 192; i += blockDim.x) {
        int j = i / 3, c = i - 3 * j;
        int cc = (c == 0) ? 0 : ((c == 1) ? 3 : 9);
        s_w3[i] = fw3[j * 15 + cc];
    }
    if (threadIdx.x < 3) {
        int cc = (threadIdx.x == 0) ? 0 : ((threadIdx.x == 1) ? 3 : 9);
        s_b3[threadIdx.x] = fb3[cc];
    }
    for (int i = threadIdx.x; i < 3 * 1024; i += blockDim.x) {
        int l = i >> 10, r = i & 1023;
        int p = (l == 0) ? 0 : ((l == 1) ? 3 : 9);
        s_tpw[i] = tpw[p * 1024 + r];
    }
    __syncthreads();
    int e = blockIdx.x * blockDim.x + threadIdx.x;
    if (e >= E) return;
    int s = esrc[e], d = edst[e];
    int g = batch[s];
    float sh0 = shifts[e * 3 + 0], sh1 = shifts[e * 3 + 1], sh2 = shifts[e * 3 + 2];
    const float* cg = cell + g * 9;
    float sv0 = sh0 * cg[0] + sh1 * cg[3] + sh2 * cg[6];
    float sv1 = sh0 * cg[1] + sh1 * cg[4] + sh2 * cg[7];
    float sv2 = sh0 * cg[2] + sh1 * cg[5] + sh2 * cg[8];
    float vx = pos[d * 3 + 0] - pos[s * 3 + 0] + sv0;
    float vy = pos[d * 3 + 1] - pos[s * 3 + 1] + sv1;
    float vz = pos[d * 3 + 2] - pos[s * 3 + 2] + sv2;
    float len = sqrtf(vx * vx + vy * vy + vz * vz);
    float inv = 1.0f / fmaxf(len, 1e-8f);
    float nx = vx * inv, ny = vy * inv, nz = vz * inv;
    float r = len * (17.0f / 5.0f);
    float h[64];
    #pragma unroll
    for (int j = 0; j < 64; j++) h[j] = s_b1[j];
    #pragma unroll 1
    for (int k = 0; k < 16; k++) {
        float dk = r - (float)(k + 1);
        float ek = __expf(-dk * dk) * (4.0f / 1.12f);
        #pragma unroll
        for (int j = 0; j < 64; j++) h[j] += ek * s_w1[k * 64 + j];
    }
    #pragma unroll
    for (int j = 0; j < 64; j++) h[j] = silu_f(h[j]);
    float g0 = s_b3[0], g1 = s_b3[1], g2 = s_b3[2];
    #pragma unroll 2
    for (int j = 0; j < 64; j++) {
        float a = s_b2[j];
        #pragma unroll
        for (int k = 0; k < 64; k++) a += h[k] * s_w2[k * 64 + j];
        a = silu_f(a);
        g0 += a * s_w3[j * 3 + 0];
        g1 += a * s_w3[j * 3 + 1];
        g2 += a * s_w3[j * 3 + 2];
    }
    g0 *= 0.125f; g1 *= 0.125f; g2 *= 0.125f;
    float t0[16], t1[16], t2[16];
    #pragma unroll
    for (int w = 0; w < 16; w++) { t0[w] = 0.f; t1[w] = 0.f; t2[w] = 0.f; }
    int s8 = s * MUL, d8 = d * MUL;
    float Ad[8];
    #pragma unroll
    for (int v = 0; v < 8; v++) Ad[v] = Ai[d8 + v];
    #pragma unroll 1
    for (int u = 0; u < 8; u++) {
        float asu = Ai[s8 + u];
        int offp = u * 128;
        #pragma unroll
        for (int v = 0; v < 8; v++) {
            float p = asu * Ad[v];
            int o2 = offp + v * 16;
            #pragma unroll
            for (int w = 0; w < 16; w++) {
                t0[w] += p * s_tpw[o2 + w];
                t1[w] += p * s_tpw[1024 + o2 + w];
                t2[w] += p * s_tpw[2048 + o2 + w];
            }
        }
    }
    #pragma unroll
    for (int w = 0; w < 16; w++) { t0[w] *= g0; t1[w] *= g1; t2[w] *= g2; }
    const float s3 = 1.7320508075688772f;
    const float s15 = 3.872983346207417f;
    const float s5h = 1.118033988749895f;
    float y1_[3] = { s3 * nx, s3 * ny, s3 * nz };
    float y2_[5] = { s15 * nx * ny, s15 * ny * nz, s5h * (3.f * nz * nz - 1.f),
                     s15 * nx * nz, 0.5f * s15 * (nx * nx - ny * ny) };
    float* o = out + (size_t)d * NCOL;
    #pragma unroll
    for (int w = 0; w < 16; w++) atomicAdd(o + w, t0[w]);
    #pragma unroll
    for (int w = 0; w < 16; w++)
        #pragma unroll
        for (int i = 0; i < 3; i++) atomicAdd(o + 16 + w * 3 + i, t1[w] * y1_[i]);
    #pragma unroll
    for (int w = 0; w < 16; w++)
        #pragma unroll
        for (int i = 0; i < 5; i++) atomicAdd(o + 64 + w * 5 + i, t2[w] * y2_[i]);
    atomicAdd(deg + d, 1.0f);
}

__global__ void finalize_kernel(float* __restrict__ out, const float* __restrict__ deg, int total) {
    int idx = blockIdx.x * blockDim.x + threadIdx.x;
    if (idx >= total) return;
    int n = idx / NCOL;
    out[idx] = out[idx] / fmaxf(deg[n], 1.0f);
}

extern "C" void kernel_launch(void* const* d_in, const int* in_sizes, int n_in,
                              void* d_out, int out_size, void* d_ws, size_t ws_size,
                              hipStream_t stream) {
    const float* pos    = (const float*)d_in[0];
    const int*   A      = (const int*)d_in[1];
    const int*   batch  = (const int*)d_in[2];
    const int*   esrc   = (const int*)d_in[3];
    const int*   edst   = (const int*)d_in[4];
    const float* shifts = (const float*)d_in[5];
    const float* cellp  = (const float*)d_in[6];
    const float* embt   = (const float*)d_in[7];
    const float* aw1    = (const float*)d_in[8];
    const float* ab1    = (const float*)d_in[9];
    const float* aw2    = (const float*)d_in[10];
    const float* ab2    = (const float*)d_in[11];
    const float* fw1    = (const float*)d_in[12];
    const float* fb1    = (const float*)d_in[13];
    const float* fw2    = (const float*)d_in[14];
    const float* fb2    = (const float*)d_in[15];
    const float* fw3    = (const float*)d_in[16];
    const float* fb3    = (const float*)d_in[17];
    const float* tpw    = (const float*)d_in[18];

    int N = in_sizes[1];
    int E = in_sizes[3];
    float* out = (float*)d_out;

    // ws layout: Ai[N*8] | count[N] | cursor[N] | off[N+1] | list[E] | gtab[TSIZE float4]
    size_t need = (size_t)N * 32 + (size_t)N * 8 + (size_t)(N + 1) * 4
                + (size_t)E * 4 + (size_t)TSIZE * 16 + 512;

    if (ws_size >= need) {
        float*  Ai     = (float*)d_ws;
        int*    count  = (int*)(Ai + (size_t)N * MUL);
        int*    cursor = count + N;
        int*    off    = cursor + N;
        int*    list   = off + (N + 1);
        float4* gtab   = (float4*)(((uintptr_t)(list + E) + 255) & ~(uintptr_t)255);

        hipMemsetAsync(count, 0, (size_t)N * 2 * sizeof(int), stream);  // count + cursor

        node_mlp_kernel<<<(N + 255) / 256, 256, 0, stream>>>(A, embt, aw1, ab1, aw2, ab2, Ai, N);
        gate_table_kernel<<<TSIZE / 256, 256, 0, stream>>>(fw1, fb1, fw2, fb2, fw3, fb3, gtab);
        count_kernel<<<(E + 255) / 256, 256, 0, stream>>>(edst, count, E);
        scan_kernel<<<1, 1024, 0, stream>>>(count, off, N);
        fill_kernel<<<(E + 255) / 256, 256, 0, stream>>>(edst, off, cursor, list, E);

        conv_node_kernel<<<(N + 3) / 4, 256, 0, stream>>>(
            pos, batch, esrc, shifts, cellp, tpw, gtab, Ai, off, list, out, N);
    } else {
        float* Ai  = (float*)d_ws;
        float* deg = Ai + (size_t)N * MUL;
        hipMemsetAsync(out, 0, (size_t)out_size * sizeof(float), stream);
        hipMemsetAsync(deg, 0, (size_t)N * sizeof(float), stream);
        node_mlp_kernel<<<(N + 255) / 256, 256, 0, stream>>>(A, embt, aw1, ab1, aw2, ab2, Ai, N);
        edge_atomic_kernel<<<(E + 255) / 256, 256, 0, stream>>>(
            pos, batch, esrc, edst, shifts, cellp,
            fw1, fb1, fw2, fb2, fw3, fb3, tpw, Ai, out, deg, E);
        int total = N * NCOL;
        finalize_kernel<<<(total + 255) / 256, 256, 0, stream>>>(out, deg, total);
    }
}